// Round 1
// 379.228 us; speedup vs baseline: 1.0436x; 1.0436x over previous
//
#include <hip/hip_runtime.h>

// B=8, T=2048, C=1024, H=1024 single-head causal self-attention.
// R5: QKV GEMM rewritten as 256x256-tile / 8-wave / BK=32 kernel with a
// 3-slot LDS ring and a COUNTED vmcnt(4) gate (loads stay 2 iterations in
// flight, never drained to 0 in the main loop), XOR bank swizzle applied as
// pre-swizzled global source + swizzled ds_read (rule #21), setprio around
// the MFMA cluster, and XCD-chunked block swizzle. Scores/PV keep the
// verified 128^2 mainloop from R4.
//   1) cvt x -> bf16          2) cvt+transpose W* -> Wt [3072,1024]
//   3) QKV gemm -> Q,K,V      4) Vt[b][h][t] = V[b][t][h]
//   5) zero l                 6) E = exp(scale*Q K^T) masked, l += rowsum
//   7) out = (E @ V) / l

#define BM 128
#define BN 128
#define BK 32

typedef __attribute__((ext_vector_type(8))) __bf16 bf16x8;
typedef __attribute__((ext_vector_type(4))) float floatx4;

__device__ __forceinline__ unsigned short f2bf(float f) {
  unsigned int u = __float_as_uint(f);
  u += 0x7fffu + ((u >> 16) & 1u);   // round-to-nearest-even
  return (unsigned short)(u >> 16);
}
__device__ __forceinline__ float bf2f(unsigned short s) {
  return __uint_as_float(((unsigned int)s) << 16);
}

// global -> LDS direct DMA, 16B per lane. LDS dest is wave-uniform base + lane*16.
__device__ __forceinline__ void gload_lds16(const unsigned short* g, unsigned short* l) {
  __builtin_amdgcn_global_load_lds(
      (const __attribute__((address_space(1))) void*)g,
      (__attribute__((address_space(3))) void*)l,
      16, 0, 0);
}

// ---------------- old 128x128 mainloop (scores / PV) ----------------

__device__ __forceinline__ void gemm_mainloop(
    const unsigned short* __restrict__ A, int lda,
    const unsigned short* __restrict__ Bt, int ldb,
    int m0, int n0, int kTiles,
    unsigned short* As, unsigned short* Bs,
    floatx4 (&acc)[4][4])
{
  const int tid  = threadIdx.x;
  const int wave = tid >> 6;
  const int lane = tid & 63;
  const int wr = wave >> 1;
  const int wc = wave & 1;

  const int c0 = wave * 2;
  const int c1 = c0 + 1;
  const int r0 = c0 * 16 + (lane >> 2);
  const int r1 = c1 * 16 + (lane >> 2);
  const int ck = (lane & 3) * 8;

  const unsigned short* pA0 = A  + (size_t)(m0 + r0) * lda + ck;
  const unsigned short* pA1 = A  + (size_t)(m0 + r1) * lda + ck;
  const unsigned short* pB0 = Bt + (size_t)(n0 + r0) * ldb + ck;
  const unsigned short* pB1 = Bt + (size_t)(n0 + r1) * ldb + ck;

  unsigned short* lA0 = As + c0 * 512;
  unsigned short* lA1 = As + c1 * 512;
  unsigned short* lB0 = Bs + c0 * 512;
  unsigned short* lB1 = Bs + c1 * 512;

  const int fr = lane & 15;
  const int kq = (lane >> 4) * 8;

  for (int kt = 0; kt < kTiles; ++kt) {
    __syncthreads();
    gload_lds16(pA0, lA0);
    gload_lds16(pA1, lA1);
    gload_lds16(pB0, lB0);
    gload_lds16(pB1, lB1);
    pA0 += BK; pA1 += BK; pB0 += BK; pB1 += BK;
    __syncthreads();

    bf16x8 af[4], bg[4];
#pragma unroll
    for (int i = 0; i < 4; ++i)
      af[i] = *(const bf16x8*)(As + ((wr * 64 + i * 16 + fr) * BK + kq));
#pragma unroll
    for (int j = 0; j < 4; ++j)
      bg[j] = *(const bf16x8*)(Bs + ((wc * 64 + j * 16 + fr) * BK + kq));
#pragma unroll
    for (int i = 0; i < 4; ++i)
#pragma unroll
      for (int j = 0; j < 4; ++j)
        acc[i][j] = __builtin_amdgcn_mfma_f32_16x16x32_bf16(af[i], bg[j], acc[i][j], 0, 0, 0);
  }
}

#define ACC_INIT(acc)                         \
  do {                                        \
    floatx4 z_ = {0.f, 0.f, 0.f, 0.f};        \
    _Pragma("unroll")                         \
    for (int i_ = 0; i_ < 4; ++i_)            \
      _Pragma("unroll")                       \
      for (int j_ = 0; j_ < 4; ++j_)          \
        acc[i_][j_] = z_;                     \
  } while (0)

// ---------------- kernels ----------------

__global__ void cvt_x_kernel(const float* __restrict__ x, unsigned short* __restrict__ xb) {
  int idx = (blockIdx.x * 256 + threadIdx.x) * 4;
  float4 v = *(const float4*)(x + idx);
  ushort4 o;
  o.x = f2bf(v.x); o.y = f2bf(v.y); o.z = f2bf(v.z); o.w = f2bf(v.w);
  *(ushort4*)(xb + idx) = o;
}

// W: [1024 (k), 1024 (n)] f32  ->  Wt: [1024 (n), 1024 (k)] bf16
__global__ void cvt_w_kernel(const float* __restrict__ W, unsigned short* __restrict__ Wt) {
  __shared__ unsigned short tile[64][65];
  const int k0 = blockIdx.x * 64, n0 = blockIdx.y * 64;
  const int tid = threadIdx.x, tx = tid & 63, ty = tid >> 6;
#pragma unroll
  for (int r = 0; r < 64; r += 4)
    tile[r + ty][tx] = f2bf(W[(size_t)(k0 + r + ty) * 1024 + (n0 + tx)]);
  __syncthreads();
#pragma unroll
  for (int r = 0; r < 64; r += 4)
    Wt[(size_t)(n0 + r + ty) * 1024 + (k0 + tx)] = tile[tx][r + ty];
}

__global__ void zero_l_kernel(float* __restrict__ l) {
  l[blockIdx.x * 256 + threadIdx.x] = 0.f;
}

// ---------------- R5: QKV 256x256 counted-vmcnt pipeline ----------------
// [Q|K|V] = xb [16384,1024] @ Wt[3072,1024]^T, scattered to 3 ld-1024 buffers.
//
// Geometry: 256x256 tile, BK=32, 512 thr = 8 waves (2 wr x 4 wc), wave tile
// 128x64 (acc[8][4]). LDS ring: 3 slots x (A 256x32 + B 256x32) bf16 = 96 KB.
// Iter kt: ds_read slot kt%3, stage K-tile kt+2 into slot (kt+2)%3,
// gate = s_waitcnt vmcnt(4) (previous iter's 4 loads) + s_barrier.
// Loads therefore have ~2 full iterations in flight -> HBM latency covered;
// vmcnt never drains to 0 in the steady loop (T3+T4).
//
// Swizzle (T2, rule #21 both-sides): LDS row = 64B = 4 x 16B chunks.
// Content(r,c) = global chunk c^(r&3): achieved by pre-swizzling the GLOBAL
// source address per lane (gload_lds dest must stay linear); ds_read uses
// chunk q^(r&3). Each consecutive-8-lane group of ds_read_b128 then hits
// 4 bank-groups 2-way (free, m136) instead of 8-way.
__global__ __launch_bounds__(512, 2) void gemm_qkv_kernel(
    const unsigned short* __restrict__ xb,
    const unsigned short* __restrict__ Wt,
    unsigned short* __restrict__ Q,
    unsigned short* __restrict__ K,
    unsigned short* __restrict__ V)
{
  // 3 A slots @ 8192 ushorts, then 3 B slots @ 8192 ushorts = 96 KB.
  __shared__ __align__(16) unsigned short lds[49152];

  // XCD-chunked swizzle: 768 blocks (64 m-tiles x 12 n-tiles), 768 % 8 == 0.
  // Blocks resident on one XCD get consecutive lin -> shared B panel in L2.
  const int bid = blockIdx.x;
  const int lin = (bid & 7) * 96 + (bid >> 3);
  const int ni = lin >> 6;            // 0..11
  const int mi = lin & 63;            // 0..63
  const int m0 = mi * 256;
  const int n0 = ni * 256;

  const int tid = threadIdx.x;
  const int w = tid >> 6;             // wave 0..7
  const int l = tid & 63;
  const int wr = w >> 2;              // 0..1 -> rows wr*128..+128
  const int wc = w & 3;               // 0..3 -> cols wc*64..+64

  // ---- staging addresses (per-lane global, pre-swizzled; wave-uniform LDS) ----
  const int sr0 = w * 16 + (l >> 2);          // rows 0..127   (stage instr 0)
  const int sr1 = 128 + sr0;                  // rows 128..255 (stage instr 1)
  const int sc  = l & 3;                      // 16B chunk within 64B row
  const int scs = ((sc ^ (sr0 & 3)) << 3);    // swizzled ushort col offset (sr1&3==sr0&3)

  const unsigned short* pA0 = xb + (size_t)(m0 + sr0) * 1024 + scs;
  const unsigned short* pA1 = xb + (size_t)(m0 + sr1) * 1024 + scs;
  const unsigned short* pB0 = Wt + (size_t)(n0 + sr0) * 1024 + scs;
  const unsigned short* pB1 = Wt + (size_t)(n0 + sr1) * 1024 + scs;

  const int stgW = w * 512;                   // wave's dest rows (w*16)*32 ushorts

#define QKV_STAGE(slot)                                          \
  do {                                                           \
    unsigned short* _sA = &lds[(slot) * 8192 + stgW];            \
    unsigned short* _sB = &lds[24576 + (slot) * 8192 + stgW];    \
    gload_lds16(pA0, _sA);                                       \
    gload_lds16(pA1, _sA + 4096);                                \
    gload_lds16(pB0, _sB);                                       \
    gload_lds16(pB1, _sB + 4096);                                \
    pA0 += 32; pA1 += 32; pB0 += 32; pB1 += 32;                  \
  } while (0)

  // ---- compute-side fragment addressing ----
  const int fr = l & 15;              // fragment row
  const int q  = l >> 4;              // k quad -> chunk q (pre-swizzle)
  const int cks = (q ^ (fr & 3)) * 8; // swizzled ushort offset within row
  const int aOff = (wr * 128 + fr) * 32 + cks;   // + i*512 per m-frag
  const int bOff = (wc * 64 + fr) * 32 + cks;    // + j*512 per n-frag

  floatx4 acc[8][4];
  {
    floatx4 z = {0.f, 0.f, 0.f, 0.f};
#pragma unroll
    for (int i = 0; i < 8; ++i)
#pragma unroll
      for (int j = 0; j < 4; ++j)
        acc[i][j] = z;
  }

  // ---- prologue: stage K-tiles 0,1; gate on tile 0 only ----
  QKV_STAGE(0);
  QKV_STAGE(1);
  asm volatile("s_waitcnt vmcnt(4)" ::: "memory");   // tile 0 done, tile 1 in flight
  __builtin_amdgcn_s_barrier();

  int curSlot = 0, swSlot = 2;
  for (int kt = 0; kt < 32; ++kt) {
    const unsigned short* sA = &lds[curSlot * 8192];
    const unsigned short* sB = &lds[24576 + curSlot * 8192];

    bf16x8 a[8], b[4];
#pragma unroll
    for (int i = 0; i < 8; ++i)
      a[i] = *(const bf16x8*)(sA + aOff + i * 512);
#pragma unroll
    for (int j = 0; j < 4; ++j)
      b[j] = *(const bf16x8*)(sB + bOff + j * 512);

    if (kt < 30) QKV_STAGE(swSlot);       // K-tile kt+2, 4 loads in flight

    __builtin_amdgcn_s_setprio(1);
#pragma unroll
    for (int i = 0; i < 8; ++i)
#pragma unroll
      for (int j = 0; j < 4; ++j)
        acc[i][j] = __builtin_amdgcn_mfma_f32_16x16x32_bf16(a[i], b[j], acc[i][j], 0, 0, 0);
    __builtin_amdgcn_s_setprio(0);

    if (kt < 31) {
      // gate for K-tile kt+1: its 4 loads (issued last iter) are the oldest;
      // this iter's 4 (tile kt+2) stay in flight -> counted, never drain-0.
      if (kt < 30) asm volatile("s_waitcnt vmcnt(4)" ::: "memory");
      else         asm volatile("s_waitcnt vmcnt(0)" ::: "memory");
      __builtin_amdgcn_s_barrier();
    }
    curSlot = (curSlot == 2) ? 0 : curSlot + 1;
    swSlot  = (swSlot  == 2) ? 0 : swSlot  + 1;
  }
#undef QKV_STAGE

  // ---- epilogue scatter: n0 block lies entirely in one of Q/K/V ----
  unsigned short* const dsts[3] = {Q, K, V};
  unsigned short* D = dsts[n0 >> 10];
  const int ncol0 = n0 & 1023;

  const int rb = m0 + wr * 128 + (q << 2);
  const int cb = ncol0 + wc * 64 + fr;
#pragma unroll
  for (int i = 0; i < 8; ++i)
#pragma unroll
    for (int j = 0; j < 4; ++j)
#pragma unroll
      for (int r = 0; r < 4; ++r)
        D[(size_t)(rb + i * 16 + r) * 1024 + (cb + j * 16)] = f2bf(acc[i][j][r]);
}

// Vt[b][h][t] = V[b*2048+t][h], ushort4 loads/stores
__global__ void transpose_v_kernel(const unsigned short* __restrict__ V,
                                   unsigned short* __restrict__ Vt) {
  __shared__ unsigned short tile[64][68];
  const int b = blockIdx.z;
  const int t0 = blockIdx.x * 64, h0 = blockIdx.y * 64;
  const int tid = threadIdx.x;
  const int cx = (tid & 15) * 4;
  const int ry = tid >> 4;               // 0..15
  const unsigned short* Vb = V + (size_t)b * 2048 * 1024;
#pragma unroll
  for (int r = 0; r < 64; r += 16) {
    ushort4 v = *(const ushort4*)(Vb + (size_t)(t0 + r + ry) * 1024 + (h0 + cx));
    *(ushort4*)&tile[r + ry][cx] = v;
  }
  __syncthreads();
  unsigned short* Vtb = Vt + (size_t)b * 1024 * 2048;
#pragma unroll
  for (int r = 0; r < 64; r += 16) {
    const int h = r + ry;
    ushort4 o;
    o.x = tile[cx][h]; o.y = tile[cx + 1][h]; o.z = tile[cx + 2][h]; o.w = tile[cx + 3][h];
    *(ushort4*)(Vtb + (size_t)(h0 + h) * 2048 + (t0 + cx)) = o;
  }
}

// E[b] = exp(scale * Q[b] K[b]^T), causal; l[b,i] += row sums.
// grid 8*136; b = blk & 7 (batch -> XCD), t = blk >> 3 (tri-tile, mi-grouped).
__global__ __launch_bounds__(256) void gemm_scores_kernel(
    const unsigned short* __restrict__ Q,
    const unsigned short* __restrict__ K,
    unsigned short* __restrict__ S,
    float* __restrict__ lsum)
{
  const int b = blockIdx.x & 7;
  const int t = blockIdx.x >> 3;
  int mi = (int)((sqrtf(8.f * (float)t + 1.f) - 1.f) * 0.5f);
  while ((mi + 1) * (mi + 2) / 2 <= t) ++mi;   // fp guard
  while (mi * (mi + 1) / 2 > t) --mi;
  const int ni = t - mi * (mi + 1) / 2;
  const int m0 = mi * BM;
  const int n0 = ni * BN;

  __shared__ __align__(16) unsigned short As[BM * BK];
  __shared__ __align__(16) unsigned short Bs[BN * BK];
  floatx4 acc[4][4];
  ACC_INIT(acc);
  const unsigned short* Qb = Q + (size_t)b * 2048 * 1024;
  const unsigned short* Kb = K + (size_t)b * 2048 * 1024;
  gemm_mainloop(Qb, 1024, Kb, 1024, m0, n0, 1024 / BK, As, Bs, acc);

  unsigned short* Sb = S + (size_t)b * 2048 * 2048;
  float* lb = lsum + b * 2048;
  const int tid = threadIdx.x, wave = tid >> 6, lane = tid & 63;
  const int wr = wave >> 1, wc = wave & 1;
  const int rb = m0 + wr * 64 + ((lane >> 4) << 2);
  const int cb = n0 + wc * 64 + (lane & 15);

  float rsum[4][4];
#pragma unroll
  for (int i = 0; i < 4; ++i)
#pragma unroll
    for (int r = 0; r < 4; ++r)
      rsum[i][r] = 0.f;

#pragma unroll
  for (int i = 0; i < 4; ++i)
#pragma unroll
    for (int j = 0; j < 4; ++j)
#pragma unroll
      for (int r = 0; r < 4; ++r) {
        const int tq = rb + i * 16 + r;
        const int tk = cb + j * 16;
        float e = 0.f;
        if (tk <= tq) e = __expf(acc[i][j][r] * 0.03125f);  // scale = 1/32
        const unsigned short h = f2bf(e);
        Sb[(size_t)tq * 2048 + tk] = h;
        rsum[i][r] += bf2f(h);   // l consistent with stored bf16 E
      }

  // reduce across the 16 lanes of each quad (same rows, different cols)
#pragma unroll
  for (int off = 1; off < 16; off <<= 1)
#pragma unroll
    for (int i = 0; i < 4; ++i)
#pragma unroll
      for (int r = 0; r < 4; ++r)
        rsum[i][r] += __shfl_xor(rsum[i][r], off, 64);

  if ((lane & 15) == 0) {
#pragma unroll
    for (int i = 0; i < 4; ++i)
#pragma unroll
      for (int r = 0; r < 4; ++r)
        atomicAdd(&lb[rb + i * 16 + r], rsum[i][r]);
  }
}

// out[b] = (E[b] @ V[b]) / l. b = blk & 7 (batch -> XCD), heavy mi first.
__global__ __launch_bounds__(256) void gemm_pv_kernel(
    const unsigned short* __restrict__ S,
    const unsigned short* __restrict__ Vt,
    const float* __restrict__ lsum,
    float* __restrict__ out)
{
  const int b = blockIdx.x & 7;
  const int r2 = blockIdx.x >> 3;              // 0..127
  const int mi = 15 - (r2 >> 3);               // heavy first (LPT)
  const int ni = r2 & 7;
  const int m0 = mi * BM;
  const int n0 = ni * BN;

  __shared__ __align__(16) unsigned short As[BM * BK];
  __shared__ __align__(16) unsigned short Bs[BN * BK];
  floatx4 acc[4][4];
  ACC_INIT(acc);
  const unsigned short* Pb = S  + (size_t)b * 2048 * 2048;   // lda 2048
  const unsigned short* Vb = Vt + (size_t)b * 1024 * 2048;   // ldb 2048
  const int kTiles = m0 / BK + BM / BK;                      // tk <= m0+127
  gemm_mainloop(Pb, 2048, Vb, 2048, m0, n0, kTiles, As, Bs, acc);

  float* Ob = out + (size_t)b * 2048 * 1024;
  const float* lb = lsum + b * 2048;
  const int tid = threadIdx.x, wave = tid >> 6, lane = tid & 63;
  const int wr = wave >> 1, wc = wave & 1;
  const int rb = m0 + wr * 64 + ((lane >> 4) << 2);
  const int cb = n0 + wc * 64 + (lane & 15);

  float inv[4][4];
#pragma unroll
  for (int i = 0; i < 4; ++i)
#pragma unroll
    for (int r = 0; r < 4; ++r)
      inv[i][r] = 1.0f / lb[rb + i * 16 + r];

#pragma unroll
  for (int i = 0; i < 4; ++i)
#pragma unroll
    for (int j = 0; j < 4; ++j)
#pragma unroll
      for (int r = 0; r < 4; ++r)
        Ob[(size_t)(rb + i * 16 + r) * 1024 + (cb + j * 16)] = acc[i][j][r] * inv[i][r];
}

// ---------------- launcher ----------------

extern "C" void kernel_launch(void* const* d_in, const int* in_sizes, int n_in,
                              void* d_out, int out_size, void* d_ws, size_t ws_size,
                              hipStream_t stream) {
  const float* x  = (const float*)d_in[0];
  const float* Wq = (const float*)d_in[1];
  const float* Wk = (const float*)d_in[2];
  const float* Wv = (const float*)d_in[3];
  float* out = (float*)d_out;

  char* ws = (char*)d_ws;
  unsigned short* xb  = (unsigned short*)(ws);                     //  33,554,432 B
  unsigned short* Wt  = (unsigned short*)(ws + 33554432ull);       //   6,291,456 B
  unsigned short* Q   = (unsigned short*)(ws + 39845888ull);       //  33,554,432 B
  unsigned short* K   = (unsigned short*)(ws + 73400320ull);       //  33,554,432 B
  unsigned short* V   = (unsigned short*)(ws + 106954752ull);      //  33,554,432 B
  unsigned short* Vt  = (unsigned short*)(ws + 140509184ull);      //  33,554,432 B
  unsigned short* S   = (unsigned short*)(ws + 174063616ull);      //  67,108,864 B
  float*          l   = (float*)ws;   // aliases xb: dead after QKV gemm
  // total ws use: 241,172,480 B

  cvt_x_kernel<<<16384, 256, 0, stream>>>(x, xb);
  dim3 gw(16, 16);
  cvt_w_kernel<<<gw, 256, 0, stream>>>(Wq, Wt);
  cvt_w_kernel<<<gw, 256, 0, stream>>>(Wk, Wt + 1024 * 1024);
  cvt_w_kernel<<<gw, 256, 0, stream>>>(Wv, Wt + 2 * 1024 * 1024);

  // 64 m-tiles x 12 n-tiles = 768 blocks (3 exact waves over 256 CUs)
  gemm_qkv_kernel<<<768, 512, 0, stream>>>(xb, Wt, Q, K, V);

  transpose_v_kernel<<<dim3(32, 16, 8), 256, 0, stream>>>(V, Vt);
  zero_l_kernel<<<64, 256, 0, stream>>>(l);   // after QKV: l aliases xb
  gemm_scores_kernel<<<8 * 136, 256, 0, stream>>>(Q, K, S, l);
  gemm_pv_kernel<<<1024, 256, 0, stream>>>(S, Vt, l, out);
}

// Round 2
// 378.720 us; speedup vs baseline: 1.0450x; 1.0013x over previous
//
#include <hip/hip_runtime.h>

// B=8, T=2048, C=1024, H=1024 single-head causal self-attention.
// R6: QKV GEMM restructured per the m201 4-phase template:
//  - per K-step (BK=32): 4 phases, each {2 ds_read prefetch (next phase's A
//    frags) || 1 global_load_lds (tile kt+2) -> barrier -> 8 MFMA -> barrier}
//  - counted gate vmcnt(3) only at phase 3 (tile kt+1 complete, kt+2's 3
//    loads stay in flight); next-tile B + a0/a1 prefetched there into the
//    ping-pong B register set (kt loop unrolled x2: all indices static)
//  - fixed XOR swizzle: chunk ^= (row>>1)&3 (old row&3 covered only 2/4
//    chunks within a 16-lane quarter -> 2x read conflict)
//  - XCD map: XCD x owns mi in [8x,8x+8) x all ni, ni-major -> concurrent
//    A working set 4MB (~L2) instead of 16MB
// Scores/PV keep the verified 128^2 mainloop.
//   1) cvt x -> bf16          2) cvt+transpose W* -> Wt [3072,1024]
//   3) QKV gemm -> Q,K,V      4) Vt[b][h][t] = V[b][t][h]
//   5) zero l                 6) E = exp(scale*Q K^T) masked, l += rowsum
//   7) out = (E @ V) / l

#define BM 128
#define BN 128
#define BK 32

typedef __attribute__((ext_vector_type(8))) __bf16 bf16x8;
typedef __attribute__((ext_vector_type(4))) float floatx4;

__device__ __forceinline__ unsigned short f2bf(float f) {
  unsigned int u = __float_as_uint(f);
  u += 0x7fffu + ((u >> 16) & 1u);   // round-to-nearest-even
  return (unsigned short)(u >> 16);
}
__device__ __forceinline__ float bf2f(unsigned short s) {
  return __uint_as_float(((unsigned int)s) << 16);
}

// global -> LDS direct DMA, 16B per lane. LDS dest is wave-uniform base + lane*16.
__device__ __forceinline__ void gload_lds16(const unsigned short* g, unsigned short* l) {
  __builtin_amdgcn_global_load_lds(
      (const __attribute__((address_space(1))) void*)g,
      (__attribute__((address_space(3))) void*)l,
      16, 0, 0);
}

// ---------------- old 128x128 mainloop (scores / PV) ----------------

__device__ __forceinline__ void gemm_mainloop(
    const unsigned short* __restrict__ A, int lda,
    const unsigned short* __restrict__ Bt, int ldb,
    int m0, int n0, int kTiles,
    unsigned short* As, unsigned short* Bs,
    floatx4 (&acc)[4][4])
{
  const int tid  = threadIdx.x;
  const int wave = tid >> 6;
  const int lane = tid & 63;
  const int wr = wave >> 1;
  const int wc = wave & 1;

  const int c0 = wave * 2;
  const int c1 = c0 + 1;
  const int r0 = c0 * 16 + (lane >> 2);
  const int r1 = c1 * 16 + (lane >> 2);
  const int ck = (lane & 3) * 8;

  const unsigned short* pA0 = A  + (size_t)(m0 + r0) * lda + ck;
  const unsigned short* pA1 = A  + (size_t)(m0 + r1) * lda + ck;
  const unsigned short* pB0 = Bt + (size_t)(n0 + r0) * ldb + ck;
  const unsigned short* pB1 = Bt + (size_t)(n0 + r1) * ldb + ck;

  unsigned short* lA0 = As + c0 * 512;
  unsigned short* lA1 = As + c1 * 512;
  unsigned short* lB0 = Bs + c0 * 512;
  unsigned short* lB1 = Bs + c1 * 512;

  const int fr = lane & 15;
  const int kq = (lane >> 4) * 8;

  for (int kt = 0; kt < kTiles; ++kt) {
    __syncthreads();
    gload_lds16(pA0, lA0);
    gload_lds16(pA1, lA1);
    gload_lds16(pB0, lB0);
    gload_lds16(pB1, lB1);
    pA0 += BK; pA1 += BK; pB0 += BK; pB1 += BK;
    __syncthreads();

    bf16x8 af[4], bg[4];
#pragma unroll
    for (int i = 0; i < 4; ++i)
      af[i] = *(const bf16x8*)(As + ((wr * 64 + i * 16 + fr) * BK + kq));
#pragma unroll
    for (int j = 0; j < 4; ++j)
      bg[j] = *(const bf16x8*)(Bs + ((wc * 64 + j * 16 + fr) * BK + kq));
#pragma unroll
    for (int i = 0; i < 4; ++i)
#pragma unroll
      for (int j = 0; j < 4; ++j)
        acc[i][j] = __builtin_amdgcn_mfma_f32_16x16x32_bf16(af[i], bg[j], acc[i][j], 0, 0, 0);
  }
}

#define ACC_INIT(acc)                         \
  do {                                        \
    floatx4 z_ = {0.f, 0.f, 0.f, 0.f};        \
    _Pragma("unroll")                         \
    for (int i_ = 0; i_ < 4; ++i_)            \
      _Pragma("unroll")                       \
      for (int j_ = 0; j_ < 4; ++j_)          \
        acc[i_][j_] = z_;                     \
  } while (0)

// ---------------- kernels ----------------

__global__ void cvt_x_kernel(const float* __restrict__ x, unsigned short* __restrict__ xb) {
  int idx = (blockIdx.x * 256 + threadIdx.x) * 4;
  float4 v = *(const float4*)(x + idx);
  ushort4 o;
  o.x = f2bf(v.x); o.y = f2bf(v.y); o.z = f2bf(v.z); o.w = f2bf(v.w);
  *(ushort4*)(xb + idx) = o;
}

// W: [1024 (k), 1024 (n)] f32  ->  Wt: [1024 (n), 1024 (k)] bf16
__global__ void cvt_w_kernel(const float* __restrict__ W, unsigned short* __restrict__ Wt) {
  __shared__ unsigned short tile[64][65];
  const int k0 = blockIdx.x * 64, n0 = blockIdx.y * 64;
  const int tid = threadIdx.x, tx = tid & 63, ty = tid >> 6;
#pragma unroll
  for (int r = 0; r < 64; r += 4)
    tile[r + ty][tx] = f2bf(W[(size_t)(k0 + r + ty) * 1024 + (n0 + tx)]);
  __syncthreads();
#pragma unroll
  for (int r = 0; r < 64; r += 4)
    Wt[(size_t)(n0 + r + ty) * 1024 + (k0 + tx)] = tile[tx][r + ty];
}

__global__ void zero_l_kernel(float* __restrict__ l) {
  l[blockIdx.x * 256 + threadIdx.x] = 0.f;
}

// ---------------- R6: QKV 256x256 4-phase counted pipeline ----------------
__global__ __launch_bounds__(512, 2) void gemm_qkv_kernel(
    const unsigned short* __restrict__ xb,
    const unsigned short* __restrict__ Wt,
    unsigned short* __restrict__ Q,
    unsigned short* __restrict__ K,
    unsigned short* __restrict__ V)
{
  // 3 slots: A at slot*8192, B at 24576 + slot*8192 (ushorts). 96 KB total.
  __shared__ __align__(16) unsigned short lds[49152];

  // XCD map: bid&7 -> XCD; XCD x owns mi in [8x, 8x+8), ni-major walk.
  const int bid = blockIdx.x;
  const int xcd = bid & 7;
  const int local = bid >> 3;              // 0..95
  const int mi = xcd * 8 + (local & 7);    // 0..63
  const int ni = local >> 3;               // 0..11
  const int m0 = mi * 256;
  const int n0 = ni * 256;

  const int tid = threadIdx.x;
  const int w = tid >> 6;
  const int l = tid & 63;
  const int wr = w >> 2;              // 0..1 -> rows wr*128
  const int wc = w & 3;               // 0..3 -> cols wc*64

  // ---- staging: per-lane pre-swizzled global src, linear LDS dest ----
  // dest row = w*16 + (l>>2), dest chunk = l&3; src chunk = (l&3)^((row>>1)&3)
  // with row>>1 & 3 == (l>>3)&3 (w*16 contributes 0 mod 4 after >>1).
  const int sr0 = w * 16 + (l >> 2);
  const int scs = (((l & 3) ^ ((l >> 3) & 3)) << 3);   // ushort offset

  const unsigned short* pA0 = xb + (size_t)(m0 + sr0) * 1024 + scs;
  const unsigned short* pA1 = xb + (size_t)(m0 + 128 + sr0) * 1024 + scs;
  const unsigned short* pB0 = Wt + (size_t)(n0 + sr0) * 1024 + scs;
  const unsigned short* pB1 = Wt + (size_t)(n0 + 128 + sr0) * 1024 + scs;

  const int stgW = w * 512;           // wave's 16 rows x 32 ushorts

#define STAGE4(slot)                                             \
  do {                                                           \
    unsigned short* _sA = &lds[(slot) * 8192 + stgW];            \
    unsigned short* _sB = &lds[24576 + (slot) * 8192 + stgW];    \
    gload_lds16(pA0, _sA);                                       \
    gload_lds16(pA1, _sA + 4096);                                \
    gload_lds16(pB0, _sB);                                       \
    gload_lds16(pB1, _sB + 4096);                                \
    pA0 += 32; pA1 += 32; pB0 += 32; pB1 += 32;                  \
  } while (0)

  // ---- compute-side fragment addressing (read with the same swizzle) ----
  const int fr = l & 15;              // fragment row
  const int q  = l >> 4;              // k quad (global chunk)
  const int cks = ((q ^ ((fr >> 1) & 3)) << 3);  // swizzled ushort offset
  const int aOff = (wr * 128 + fr) * 32 + cks;   // + i*512 per m-frag
  const int bOff = (wc * 64 + fr) * 32 + cks;    // + j*512 per n-frag

  floatx4 acc[8][4];
  {
    floatx4 z = {0.f, 0.f, 0.f, 0.f};
#pragma unroll
    for (int i = 0; i < 8; ++i)
#pragma unroll
      for (int j = 0; j < 4; ++j)
        acc[i][j] = z;
  }

  // ---- prologue: stage tiles 0,1; wait tile 0+1? no: vmcnt(4) = tile 0 ----
  STAGE4(0);
  STAGE4(1);
  asm volatile("s_waitcnt vmcnt(4)" ::: "memory");   // tile 0 landed
  __builtin_amdgcn_s_barrier();

  bf16x8 a[8], b0[4], b1[4];
  {
    const unsigned short* sA = &lds[0];
    const unsigned short* sB = &lds[24576];
#pragma unroll
    for (int j = 0; j < 4; ++j) b0[j] = *(const bf16x8*)(sB + bOff + j * 512);
    a[0] = *(const bf16x8*)(sA + aOff);
    a[1] = *(const bf16x8*)(sA + aOff + 512);
  }

#define MFMA_PAIR(I0, BU)                                                           \
  do {                                                                              \
    __builtin_amdgcn_s_setprio(1);                                                  \
    _Pragma("unroll")                                                               \
    for (int j = 0; j < 4; ++j) {                                                   \
      acc[(I0)][j] =                                                                \
          __builtin_amdgcn_mfma_f32_16x16x32_bf16(a[(I0)], BU[j], acc[(I0)][j], 0, 0, 0); \
      acc[(I0) + 1][j] =                                                            \
          __builtin_amdgcn_mfma_f32_16x16x32_bf16(a[(I0) + 1], BU[j], acc[(I0) + 1][j], 0, 0, 0); \
    }                                                                               \
    __builtin_amdgcn_s_setprio(0);                                                  \
  } while (0)

  // ITER: one K-step. Uses B-set BU, prefetches next tile's B into BP.
  // Invariants at entry: regs {a[0],a[1],BU} hold tile KT's first operands;
  // tile KT fully staged in `slot`; tile KT+1 staged except possibly in
  // flight (gated at phase 3); tile KT+2 staged during this iter.
#define ITER(KT, BU, BP)                                                  \
  do {                                                                    \
    const int nslot = (slot == 2) ? 0 : slot + 1;                         \
    const int sslot = (nslot == 2) ? 0 : nslot + 1;                       \
    const unsigned short* sA  = &lds[slot * 8192];                        \
    const unsigned short* sAn = &lds[nslot * 8192];                       \
    const unsigned short* sBn = &lds[24576 + nslot * 8192];               \
    unsigned short* dA = &lds[sslot * 8192 + stgW];                       \
    unsigned short* dB = &lds[24576 + sslot * 8192 + stgW];               \
    const bool doStage = ((KT) < 30);                                     \
    const bool doNext  = ((KT) < 31);                                     \
    /* phase 0: prefetch a2,a3 | stage A-half0(tile KT+2) | MFMA i=0,1 */ \
    a[2] = *(const bf16x8*)(sA + aOff + 2 * 512);                         \
    a[3] = *(const bf16x8*)(sA + aOff + 3 * 512);                         \
    if (doStage) gload_lds16(pA0, dA);                                    \
    __builtin_amdgcn_s_barrier();                                         \
    MFMA_PAIR(0, BU);                                                     \
    __builtin_amdgcn_s_barrier();                                         \
    /* phase 1: prefetch a4,a5 | stage A-half1 | MFMA i=2,3 */            \
    a[4] = *(const bf16x8*)(sA + aOff + 4 * 512);                         \
    a[5] = *(const bf16x8*)(sA + aOff + 5 * 512);                         \
    if (doStage) gload_lds16(pA1, dA + 4096);                             \
    __builtin_amdgcn_s_barrier();                                         \
    MFMA_PAIR(2, BU);                                                     \
    __builtin_amdgcn_s_barrier();                                         \
    /* phase 2: prefetch a6,a7 | stage B-half0 | MFMA i=4,5 */            \
    a[6] = *(const bf16x8*)(sA + aOff + 6 * 512);                         \
    a[7] = *(const bf16x8*)(sA + aOff + 7 * 512);                         \
    if (doStage) gload_lds16(pB0, dB);                                    \
    __builtin_amdgcn_s_barrier();                                         \
    MFMA_PAIR(4, BU);                                                     \
    __builtin_amdgcn_s_barrier();                                         \
    /* phase 3: counted gate; prefetch next-tile B,a0,a1; stage B-half1 */\
    if (doNext) {                                                         \
      if (doStage) asm volatile("s_waitcnt vmcnt(3)" ::: "memory");       \
      else         asm volatile("s_waitcnt vmcnt(0)" ::: "memory");       \
      __builtin_amdgcn_s_barrier();                                       \
      _Pragma("unroll")                                                   \
      for (int j = 0; j < 4; ++j)                                         \
        BP[j] = *(const bf16x8*)(sBn + bOff + j * 512);                   \
      a[0] = *(const bf16x8*)(sAn + aOff);                                \
      a[1] = *(const bf16x8*)(sAn + aOff + 512);                          \
    }                                                                     \
    if (doStage) {                                                        \
      gload_lds16(pB1, dB + 4096);                                       \
      pA0 += 32; pA1 += 32; pB0 += 32; pB1 += 32;                         \
    }                                                                     \
    MFMA_PAIR(6, BU);                                                     \
    __builtin_amdgcn_s_barrier();                                         \
    slot = nslot;                                                         \
  } while (0)

  int slot = 0;
#pragma unroll 1
  for (int kt2 = 0; kt2 < 16; ++kt2) {
    const int kt = kt2 * 2;
    ITER(kt, b0, b1);        // even: consume b0, prefetch b1
    ITER(kt + 1, b1, b0);    // odd:  consume b1, prefetch b0
  }
#undef ITER
#undef MFMA_PAIR
#undef STAGE4

  // ---- epilogue scatter: n0 block lies entirely in one of Q/K/V ----
  unsigned short* const dsts[3] = {Q, K, V};
  unsigned short* D = dsts[n0 >> 10];
  const int ncol0 = n0 & 1023;

  const int rb = m0 + wr * 128 + (q << 2);
  const int cb = ncol0 + wc * 64 + fr;
#pragma unroll
  for (int i = 0; i < 8; ++i)
#pragma unroll
    for (int j = 0; j < 4; ++j)
#pragma unroll
      for (int r = 0; r < 4; ++r)
        D[(size_t)(rb + i * 16 + r) * 1024 + (cb + j * 16)] = f2bf(acc[i][j][r]);
}

// Vt[b][h][t] = V[b*2048+t][h], ushort4 loads/stores
__global__ void transpose_v_kernel(const unsigned short* __restrict__ V,
                                   unsigned short* __restrict__ Vt) {
  __shared__ unsigned short tile[64][68];
  const int b = blockIdx.z;
  const int t0 = blockIdx.x * 64, h0 = blockIdx.y * 64;
  const int tid = threadIdx.x;
  const int cx = (tid & 15) * 4;
  const int ry = tid >> 4;               // 0..15
  const unsigned short* Vb = V + (size_t)b * 2048 * 1024;
#pragma unroll
  for (int r = 0; r < 64; r += 16) {
    ushort4 v = *(const ushort4*)(Vb + (size_t)(t0 + r + ry) * 1024 + (h0 + cx));
    *(ushort4*)&tile[r + ry][cx] = v;
  }
  __syncthreads();
  unsigned short* Vtb = Vt + (size_t)b * 1024 * 2048;
#pragma unroll
  for (int r = 0; r < 64; r += 16) {
    const int h = r + ry;
    ushort4 o;
    o.x = tile[cx][h]; o.y = tile[cx + 1][h]; o.z = tile[cx + 2][h]; o.w = tile[cx + 3][h];
    *(ushort4*)(Vtb + (size_t)(h0 + h) * 2048 + (t0 + cx)) = o;
  }
}

// E[b] = exp(scale * Q[b] K[b]^T), causal; l[b,i] += row sums.
// grid 8*136; b = blk & 7 (batch -> XCD), t = blk >> 3 (tri-tile, mi-grouped).
__global__ __launch_bounds__(256) void gemm_scores_kernel(
    const unsigned short* __restrict__ Q,
    const unsigned short* __restrict__ K,
    unsigned short* __restrict__ S,
    float* __restrict__ lsum)
{
  const int b = blockIdx.x & 7;
  const int t = blockIdx.x >> 3;
  int mi = (int)((sqrtf(8.f * (float)t + 1.f) - 1.f) * 0.5f);
  while ((mi + 1) * (mi + 2) / 2 <= t) ++mi;   // fp guard
  while (mi * (mi + 1) / 2 > t) --mi;
  const int ni = t - mi * (mi + 1) / 2;
  const int m0 = mi * BM;
  const int n0 = ni * BN;

  __shared__ __align__(16) unsigned short As[BM * BK];
  __shared__ __align__(16) unsigned short Bs[BN * BK];
  floatx4 acc[4][4];
  ACC_INIT(acc);
  const unsigned short* Qb = Q + (size_t)b * 2048 * 1024;
  const unsigned short* Kb = K + (size_t)b * 2048 * 1024;
  gemm_mainloop(Qb, 1024, Kb, 1024, m0, n0, 1024 / BK, As, Bs, acc);

  unsigned short* Sb = S + (size_t)b * 2048 * 2048;
  float* lb = lsum + b * 2048;
  const int tid = threadIdx.x, wave = tid >> 6, lane = tid & 63;
  const int wr = wave >> 1, wc = wave & 1;
  const int rb = m0 + wr * 64 + ((lane >> 4) << 2);
  const int cb = n0 + wc * 64 + (lane & 15);

  float rsum[4][4];
#pragma unroll
  for (int i = 0; i < 4; ++i)
#pragma unroll
    for (int r = 0; r < 4; ++r)
      rsum[i][r] = 0.f;

#pragma unroll
  for (int i = 0; i < 4; ++i)
#pragma unroll
    for (int j = 0; j < 4; ++j)
#pragma unroll
      for (int r = 0; r < 4; ++r) {
        const int tq = rb + i * 16 + r;
        const int tk = cb + j * 16;
        float e = 0.f;
        if (tk <= tq) e = __expf(acc[i][j][r] * 0.03125f);  // scale = 1/32
        const unsigned short h = f2bf(e);
        Sb[(size_t)tq * 2048 + tk] = h;
        rsum[i][r] += bf2f(h);   // l consistent with stored bf16 E
      }

  // reduce across the 16 lanes of each quad (same rows, different cols)
#pragma unroll
  for (int off = 1; off < 16; off <<= 1)
#pragma unroll
    for (int i = 0; i < 4; ++i)
#pragma unroll
      for (int r = 0; r < 4; ++r)
        rsum[i][r] += __shfl_xor(rsum[i][r], off, 64);

  if ((lane & 15) == 0) {
#pragma unroll
    for (int i = 0; i < 4; ++i)
#pragma unroll
      for (int r = 0; r < 4; ++r)
        atomicAdd(&lb[rb + i * 16 + r], rsum[i][r]);
  }
}

// out[b] = (E[b] @ V[b]) / l. b = blk & 7 (batch -> XCD), heavy mi first.
__global__ __launch_bounds__(256) void gemm_pv_kernel(
    const unsigned short* __restrict__ S,
    const unsigned short* __restrict__ Vt,
    const float* __restrict__ lsum,
    float* __restrict__ out)
{
  const int b = blockIdx.x & 7;
  const int r2 = blockIdx.x >> 3;              // 0..127
  const int mi = 15 - (r2 >> 3);               // heavy first (LPT)
  const int ni = r2 & 7;
  const int m0 = mi * BM;
  const int n0 = ni * BN;

  __shared__ __align__(16) unsigned short As[BM * BK];
  __shared__ __align__(16) unsigned short Bs[BN * BK];
  floatx4 acc[4][4];
  ACC_INIT(acc);
  const unsigned short* Pb = S  + (size_t)b * 2048 * 2048;   // lda 2048
  const unsigned short* Vb = Vt + (size_t)b * 1024 * 2048;   // ldb 2048
  const int kTiles = m0 / BK + BM / BK;                      // tk <= m0+127
  gemm_mainloop(Pb, 2048, Vb, 2048, m0, n0, kTiles, As, Bs, acc);

  float* Ob = out + (size_t)b * 2048 * 1024;
  const float* lb = lsum + b * 2048;
  const int tid = threadIdx.x, wave = tid >> 6, lane = tid & 63;
  const int wr = wave >> 1, wc = wave & 1;
  const int rb = m0 + wr * 64 + ((lane >> 4) << 2);
  const int cb = n0 + wc * 64 + (lane & 15);

  float inv[4][4];
#pragma unroll
  for (int i = 0; i < 4; ++i)
#pragma unroll
    for (int r = 0; r < 4; ++r)
      inv[i][r] = 1.0f / lb[rb + i * 16 + r];

#pragma unroll
  for (int i = 0; i < 4; ++i)
#pragma unroll
    for (int j = 0; j < 4; ++j)
#pragma unroll
      for (int r = 0; r < 4; ++r)
        Ob[(size_t)(rb + i * 16 + r) * 1024 + (cb + j * 16)] = acc[i][j][r] * inv[i][r];
}

// ---------------- launcher ----------------

extern "C" void kernel_launch(void* const* d_in, const int* in_sizes, int n_in,
                              void* d_out, int out_size, void* d_ws, size_t ws_size,
                              hipStream_t stream) {
  const float* x  = (const float*)d_in[0];
  const float* Wq = (const float*)d_in[1];
  const float* Wk = (const float*)d_in[2];
  const float* Wv = (const float*)d_in[3];
  float* out = (float*)d_out;

  char* ws = (char*)d_ws;
  unsigned short* xb  = (unsigned short*)(ws);                     //  33,554,432 B
  unsigned short* Wt  = (unsigned short*)(ws + 33554432ull);       //   6,291,456 B
  unsigned short* Q   = (unsigned short*)(ws + 39845888ull);       //  33,554,432 B
  unsigned short* K   = (unsigned short*)(ws + 73400320ull);       //  33,554,432 B
  unsigned short* V   = (unsigned short*)(ws + 106954752ull);      //  33,554,432 B
  unsigned short* Vt  = (unsigned short*)(ws + 140509184ull);      //  33,554,432 B
  unsigned short* S   = (unsigned short*)(ws + 174063616ull);      //  67,108,864 B
  float*          l   = (float*)ws;   // aliases xb: dead after QKV gemm
  // total ws use: 241,172,480 B

  cvt_x_kernel<<<16384, 256, 0, stream>>>(x, xb);
  dim3 gw(16, 16);
  cvt_w_kernel<<<gw, 256, 0, stream>>>(Wq, Wt);
  cvt_w_kernel<<<gw, 256, 0, stream>>>(Wk, Wt + 1024 * 1024);
  cvt_w_kernel<<<gw, 256, 0, stream>>>(Wv, Wt + 2 * 1024 * 1024);

  // 64 m-tiles x 12 n-tiles = 768 blocks (3 exact waves over 256 CUs)
  gemm_qkv_kernel<<<768, 512, 0, stream>>>(xb, Wt, Q, K, V);

  transpose_v_kernel<<<dim3(32, 16, 8), 256, 0, stream>>>(V, Vt);
  zero_l_kernel<<<64, 256, 0, stream>>>(l);   // after QKV: l aliases xb
  gemm_scores_kernel<<<8 * 136, 256, 0, stream>>>(Q, K, S, l);
  gemm_pv_kernel<<<1024, 256, 0, stream>>>(S, Vt, l, out);
}

// Round 3
// 365.827 us; speedup vs baseline: 1.0818x; 1.0352x over previous
//
#include <hip/hip_runtime.h>

// B=8, T=2048, C=1024, H=1024 single-head causal self-attention.
// R7: QKV GEMM ported to the m201 8-phase / BK=64 / 2-buffer template:
//  - LDS 128 KB: buf{0,1} x regions {A0,A1,B0,B1} of 16 KB (128 rows x 64 k).
//  - iter j computes tiles 2j (buf0, phases 0-3) and 2j+1 (buf1, phases 4-7);
//    each phase: {ds_read 0-12 b128 || stage 1 half-tile (2 gload_lds)} ->
//    barrier -> lgkmcnt(0) -> setprio(1) -> 16 MFMA -> setprio(0) -> barrier.
//  - counted gates vmcnt(4) ONLY at phases 3 and 7 (12 outstanding -> drain
//    oldest 8 = the next tile's 4 halves; 4 stay in flight). Final iter
//    drains with vmcnt(0) at phase 3.
//  - stage schedule (iter j): p0:(2j+1).A0->buf1A0  p1:(2j+1).A1->buf1A1
//    p2:(2j+2).B0->buf0B0  p3:(2j+2).B1->buf0B1  p4:(2j+2).A0->buf0A0
//    p5:(2j+2).A1->buf0A1  p6:(2j+3).B0->buf1B0  p7:(2j+3).B1->buf1B1
//    (each region overwritten >=1 phase after its last read; each tile's
//    halves retire at the gate before its first read)
//  - swizzle for 128B rows: chunk' = c ^ (r&7), pre-swizzled global source
//    + swizzled ds_read (rule #21); conflict-free (R6 measured 0).
// Scores/PV keep the verified 128^2 mainloop.

#define BM 128
#define BN 128
#define BK 32

typedef __attribute__((ext_vector_type(8))) __bf16 bf16x8;
typedef __attribute__((ext_vector_type(4))) float floatx4;

__device__ __forceinline__ unsigned short f2bf(float f) {
  unsigned int u = __float_as_uint(f);
  u += 0x7fffu + ((u >> 16) & 1u);   // round-to-nearest-even
  return (unsigned short)(u >> 16);
}
__device__ __forceinline__ float bf2f(unsigned short s) {
  return __uint_as_float(((unsigned int)s) << 16);
}

// global -> LDS direct DMA, 16B per lane. LDS dest is wave-uniform base + lane*16.
__device__ __forceinline__ void gload_lds16(const unsigned short* g, unsigned short* l) {
  __builtin_amdgcn_global_load_lds(
      (const __attribute__((address_space(1))) void*)g,
      (__attribute__((address_space(3))) void*)l,
      16, 0, 0);
}

// ---------------- old 128x128 mainloop (scores / PV) ----------------

__device__ __forceinline__ void gemm_mainloop(
    const unsigned short* __restrict__ A, int lda,
    const unsigned short* __restrict__ Bt, int ldb,
    int m0, int n0, int kTiles,
    unsigned short* As, unsigned short* Bs,
    floatx4 (&acc)[4][4])
{
  const int tid  = threadIdx.x;
  const int wave = tid >> 6;
  const int lane = tid & 63;
  const int wr = wave >> 1;
  const int wc = wave & 1;

  const int c0 = wave * 2;
  const int c1 = c0 + 1;
  const int r0 = c0 * 16 + (lane >> 2);
  const int r1 = c1 * 16 + (lane >> 2);
  const int ck = (lane & 3) * 8;

  const unsigned short* pA0 = A  + (size_t)(m0 + r0) * lda + ck;
  const unsigned short* pA1 = A  + (size_t)(m0 + r1) * lda + ck;
  const unsigned short* pB0 = Bt + (size_t)(n0 + r0) * ldb + ck;
  const unsigned short* pB1 = Bt + (size_t)(n0 + r1) * ldb + ck;

  unsigned short* lA0 = As + c0 * 512;
  unsigned short* lA1 = As + c1 * 512;
  unsigned short* lB0 = Bs + c0 * 512;
  unsigned short* lB1 = Bs + c1 * 512;

  const int fr = lane & 15;
  const int kq = (lane >> 4) * 8;

  for (int kt = 0; kt < kTiles; ++kt) {
    __syncthreads();
    gload_lds16(pA0, lA0);
    gload_lds16(pA1, lA1);
    gload_lds16(pB0, lB0);
    gload_lds16(pB1, lB1);
    pA0 += BK; pA1 += BK; pB0 += BK; pB1 += BK;
    __syncthreads();

    bf16x8 af[4], bg[4];
#pragma unroll
    for (int i = 0; i < 4; ++i)
      af[i] = *(const bf16x8*)(As + ((wr * 64 + i * 16 + fr) * BK + kq));
#pragma unroll
    for (int j = 0; j < 4; ++j)
      bg[j] = *(const bf16x8*)(Bs + ((wc * 64 + j * 16 + fr) * BK + kq));
#pragma unroll
    for (int i = 0; i < 4; ++i)
#pragma unroll
      for (int j = 0; j < 4; ++j)
        acc[i][j] = __builtin_amdgcn_mfma_f32_16x16x32_bf16(af[i], bg[j], acc[i][j], 0, 0, 0);
  }
}

#define ACC_INIT(acc)                         \
  do {                                        \
    floatx4 z_ = {0.f, 0.f, 0.f, 0.f};        \
    _Pragma("unroll")                         \
    for (int i_ = 0; i_ < 4; ++i_)            \
      _Pragma("unroll")                       \
      for (int j_ = 0; j_ < 4; ++j_)          \
        acc[i_][j_] = z_;                     \
  } while (0)

// ---------------- kernels ----------------

__global__ void cvt_x_kernel(const float* __restrict__ x, unsigned short* __restrict__ xb) {
  int idx = (blockIdx.x * 256 + threadIdx.x) * 4;
  float4 v = *(const float4*)(x + idx);
  ushort4 o;
  o.x = f2bf(v.x); o.y = f2bf(v.y); o.z = f2bf(v.z); o.w = f2bf(v.w);
  *(ushort4*)(xb + idx) = o;
}

// W: [1024 (k), 1024 (n)] f32  ->  Wt: [1024 (n), 1024 (k)] bf16
__global__ void cvt_w_kernel(const float* __restrict__ W, unsigned short* __restrict__ Wt) {
  __shared__ unsigned short tile[64][65];
  const int k0 = blockIdx.x * 64, n0 = blockIdx.y * 64;
  const int tid = threadIdx.x, tx = tid & 63, ty = tid >> 6;
#pragma unroll
  for (int r = 0; r < 64; r += 4)
    tile[r + ty][tx] = f2bf(W[(size_t)(k0 + r + ty) * 1024 + (n0 + tx)]);
  __syncthreads();
#pragma unroll
  for (int r = 0; r < 64; r += 4)
    Wt[(size_t)(n0 + r + ty) * 1024 + (k0 + tx)] = tile[tx][r + ty];
}

__global__ void zero_l_kernel(float* __restrict__ l) {
  l[blockIdx.x * 256 + threadIdx.x] = 0.f;
}

// ---------------- R7: QKV 256x256 8-phase BK=64 pipeline ----------------
__global__ __launch_bounds__(512, 2) void gemm_qkv_kernel(
    const unsigned short* __restrict__ xb,
    const unsigned short* __restrict__ Wt,
    unsigned short* __restrict__ Q,
    unsigned short* __restrict__ K,
    unsigned short* __restrict__ V)
{
  // buf0: A0@0 A1@8192 B0@16384 B1@24576; buf1: +32768. (ushort idx, 128 KB)
  __shared__ __align__(16) unsigned short lds[65536];

  // XCD map: bid&7 -> XCD; XCD x owns mi in [8x, 8x+8), ni-major walk.
  const int bid = blockIdx.x;
  const int xcd = bid & 7;
  const int local = bid >> 3;              // 0..95
  const int mi = xcd * 8 + (local & 7);    // 0..63
  const int ni = local >> 3;               // 0..11
  const int m0 = mi * 256;
  const int n0 = ni * 256;

  const int tid = threadIdx.x;
  const int w = tid >> 6;             // wave 0..7
  const int l = tid & 63;
  const int wr = w >> 2;              // 0..1 -> rows wr*128
  const int wc = w & 3;               // 0..3 -> cols wc*64

  // ---- staging: pre-swizzled global src, linear LDS dest ----
  // stage instr covers 8 rows x 8 chunks: lane l -> row (l>>3), dest chunk l&7,
  // src chunk (l&7)^((l>>3)&7)  (row&7 == (l>>3)&7 since wave base w*8 = 0 mod 8).
  const int srcRow = w * 8 + (l >> 3);
  const int chunkSrc = (((l & 7) ^ ((l >> 3) & 7)) << 3);   // ushort offset
  const unsigned short* pAs = xb + (size_t)(m0 + srcRow) * 1024 + chunkSrc;
  const unsigned short* pBs = Wt + (size_t)(n0 + srcRow) * 1024 + chunkSrc;
  const int stgW = w * 512;           // wave's 8 rows x 64 ushorts within region

  // STG: one half-tile (128 rows x 64 k) = 2 gloads/wave. gbase at (tile,half).
#define STG(gbase, ldsOff)                                      \
  do {                                                          \
    gload_lds16((gbase), &lds[(ldsOff) + stgW]);                \
    gload_lds16((gbase) + 65536, &lds[(ldsOff) + stgW + 4096]); \
  } while (0)

  // ---- read-side fragment addressing (swizzled ds_read) ----
  const int fr = l & 15;              // fragment row
  const int kq = l >> 4;              // k-quad (chunk within K=32 sub)
  const int ac0 = ((kq)     ^ (fr & 7)) << 3;   // ks=0 swizzled ushort offset
  const int ac1 = ((4 + kq) ^ (fr & 7)) << 3;   // ks=1
  const int aBase = wr * 8192 + fr * 64;
  const int bBase = 16384 + (wc >> 1) * 8192 + ((wc & 1) * 64 + fr) * 64;

#define RD_A(BUF, MH)                                                          \
  do {                                                                         \
    _Pragma("unroll")                                                          \
    for (int f = 0; f < 4; ++f) {                                              \
      a[2*f]   = *(const bf16x8*)(lds + (BUF) + aBase + ((MH)*4+f)*1024 + ac0);\
      a[2*f+1] = *(const bf16x8*)(lds + (BUF) + aBase + ((MH)*4+f)*1024 + ac1);\
    }                                                                          \
  } while (0)
#define RD_B(BUF, NH)                                                          \
  do {                                                                         \
    _Pragma("unroll")                                                          \
    for (int n = 0; n < 2; ++n) {                                              \
      b[2*((NH)*2+n)]   = *(const bf16x8*)(lds + (BUF) + bBase + ((NH)*2+n)*1024 + ac0); \
      b[2*((NH)*2+n)+1] = *(const bf16x8*)(lds + (BUF) + bBase + ((NH)*2+n)*1024 + ac1); \
    }                                                                          \
  } while (0)

#define PH_OPEN()                                             \
  do {                                                        \
    __builtin_amdgcn_s_barrier();                             \
    asm volatile("s_waitcnt lgkmcnt(0)" ::: "memory");        \
    __builtin_amdgcn_sched_barrier(0);                        \
  } while (0)

  // 16 MFMA: quadrant (MB..MB+3) x (NB..NB+1), K=64 (2 ksubs chained per acc)
#define PH_MFMA(MB, NB)                                                        \
  do {                                                                         \
    __builtin_amdgcn_s_setprio(1);                                             \
    _Pragma("unroll")                                                          \
    for (int f = 0; f < 4; ++f)                                                \
      _Pragma("unroll")                                                        \
      for (int n = 0; n < 2; ++n) {                                            \
        acc[(MB)+f][(NB)+n] = __builtin_amdgcn_mfma_f32_16x16x32_bf16(         \
            a[2*f],   b[2*((NB)+n)],   acc[(MB)+f][(NB)+n], 0, 0, 0);          \
        acc[(MB)+f][(NB)+n] = __builtin_amdgcn_mfma_f32_16x16x32_bf16(         \
            a[2*f+1], b[2*((NB)+n)+1], acc[(MB)+f][(NB)+n], 0, 0, 0);          \
      }                                                                        \
    __builtin_amdgcn_s_setprio(0);                                             \
  } while (0)

  floatx4 acc[8][4];
  {
    floatx4 z = {0.f, 0.f, 0.f, 0.f};
#pragma unroll
    for (int i = 0; i < 8; ++i)
#pragma unroll
      for (int j = 0; j < 4; ++j)
        acc[i][j] = z;
  }
  bf16x8 a[8], b[8];

  // ---- prologue: tile0 (all 4 halves -> buf0), tile1 B halves -> buf1 ----
  STG(pAs,            0);        // t0.A0
  STG(pAs + 131072,   8192);     // t0.A1
  STG(pBs,            16384);    // t0.B0
  STG(pBs + 131072,   24576);    // t0.B1
  STG(pBs + 64,           49152);// t1.B0 -> buf1
  STG(pBs + 64 + 131072,  57344);// t1.B1
  asm volatile("s_waitcnt vmcnt(4)" ::: "memory");   // t0 landed; t1.B in flight
  __builtin_amdgcn_s_barrier();

#pragma unroll 1
  for (int j = 0; j < 8; ++j) {
    const bool st2 = (j < 7);    // stages targeting tiles 2j+2, 2j+3

    // p0: reads t(2j) A(mf0-3)+B(nf0-1); stage t(2j+1).A0 -> buf1.A0
    RD_A(0, 0); RD_B(0, 0);
    STG(pAs + 64, 32768);
    PH_OPEN();
    PH_MFMA(0, 0);
    __builtin_amdgcn_s_barrier();

    // p1: reads B(nf2-3); stage t(2j+1).A1 -> buf1.A1
    RD_B(0, 1);
    STG(pAs + 64 + 131072, 40960);
    PH_OPEN();
    PH_MFMA(0, 2);
    __builtin_amdgcn_s_barrier();

    // p2: reads A(mf4-7); stage t(2j+2).B0 -> buf0.B0
    RD_A(0, 1);
    if (st2) STG(pBs + 128, 16384);
    PH_OPEN();
    PH_MFMA(4, 0);
    __builtin_amdgcn_s_barrier();

    // p3: stage t(2j+2).B1 -> buf0.B1; MFMA; MID GATE
    if (st2) STG(pBs + 128 + 131072, 24576);
    PH_OPEN();
    PH_MFMA(4, 2);
    if (st2) asm volatile("s_waitcnt vmcnt(4)" ::: "memory");
    else     asm volatile("s_waitcnt vmcnt(0)" ::: "memory");
    __builtin_amdgcn_s_barrier();

    // p4: reads t(2j+1) A(mf0-3)+B(nf0-1) from buf1; stage t(2j+2).A0 -> buf0.A0
    RD_A(32768, 0); RD_B(32768, 0);
    if (st2) STG(pAs + 128, 0);
    PH_OPEN();
    PH_MFMA(0, 0);
    __builtin_amdgcn_s_barrier();

    // p5: reads B(nf2-3) buf1; stage t(2j+2).A1 -> buf0.A1
    RD_B(32768, 1);
    if (st2) STG(pAs + 128 + 131072, 8192);
    PH_OPEN();
    PH_MFMA(0, 2);
    __builtin_amdgcn_s_barrier();

    // p6: reads A(mf4-7) buf1; stage t(2j+3).B0 -> buf1.B0
    RD_A(32768, 1);
    if (st2) STG(pBs + 192, 49152);
    PH_OPEN();
    PH_MFMA(4, 0);
    __builtin_amdgcn_s_barrier();

    // p7: stage t(2j+3).B1 -> buf1.B1; MFMA; END GATE
    if (st2) STG(pBs + 192 + 131072, 57344);
    PH_OPEN();
    PH_MFMA(4, 2);
    if (st2) asm volatile("s_waitcnt vmcnt(4)" ::: "memory");
    __builtin_amdgcn_s_barrier();

    pAs += 128; pBs += 128;
  }
#undef STG
#undef RD_A
#undef RD_B
#undef PH_OPEN
#undef PH_MFMA

  // ---- epilogue scatter: n0 block lies entirely in one of Q/K/V ----
  unsigned short* const dsts[3] = {Q, K, V};
  unsigned short* D = dsts[n0 >> 10];
  const int ncol0 = n0 & 1023;

  const int rb = m0 + wr * 128 + (kq << 2);
  const int cb = ncol0 + wc * 64 + fr;
#pragma unroll
  for (int i = 0; i < 8; ++i)
#pragma unroll
    for (int jj = 0; jj < 4; ++jj)
#pragma unroll
      for (int r = 0; r < 4; ++r)
        D[(size_t)(rb + i * 16 + r) * 1024 + (cb + jj * 16)] = f2bf(acc[i][jj][r]);
}

// Vt[b][h][t] = V[b*2048+t][h], ushort4 loads/stores
__global__ void transpose_v_kernel(const unsigned short* __restrict__ V,
                                   unsigned short* __restrict__ Vt) {
  __shared__ unsigned short tile[64][68];
  const int b = blockIdx.z;
  const int t0 = blockIdx.x * 64, h0 = blockIdx.y * 64;
  const int tid = threadIdx.x;
  const int cx = (tid & 15) * 4;
  const int ry = tid >> 4;               // 0..15
  const unsigned short* Vb = V + (size_t)b * 2048 * 1024;
#pragma unroll
  for (int r = 0; r < 64; r += 16) {
    ushort4 v = *(const ushort4*)(Vb + (size_t)(t0 + r + ry) * 1024 + (h0 + cx));
    *(ushort4*)&tile[r + ry][cx] = v;
  }
  __syncthreads();
  unsigned short* Vtb = Vt + (size_t)b * 1024 * 2048;
#pragma unroll
  for (int r = 0; r < 64; r += 16) {
    const int h = r + ry;
    ushort4 o;
    o.x = tile[cx][h]; o.y = tile[cx + 1][h]; o.z = tile[cx + 2][h]; o.w = tile[cx + 3][h];
    *(ushort4*)(Vtb + (size_t)(h0 + h) * 2048 + (t0 + cx)) = o;
  }
}

// E[b] = exp(scale * Q[b] K[b]^T), causal; l[b,i] += row sums.
// grid 8*136; b = blk & 7 (batch -> XCD), t = blk >> 3 (tri-tile, mi-grouped).
__global__ __launch_bounds__(256) void gemm_scores_kernel(
    const unsigned short* __restrict__ Q,
    const unsigned short* __restrict__ K,
    unsigned short* __restrict__ S,
    float* __restrict__ lsum)
{
  const int b = blockIdx.x & 7;
  const int t = blockIdx.x >> 3;
  int mi = (int)((sqrtf(8.f * (float)t + 1.f) - 1.f) * 0.5f);
  while ((mi + 1) * (mi + 2) / 2 <= t) ++mi;   // fp guard
  while (mi * (mi + 1) / 2 > t) --mi;
  const int ni = t - mi * (mi + 1) / 2;
  const int m0 = mi * BM;
  const int n0 = ni * BN;

  __shared__ __align__(16) unsigned short As[BM * BK];
  __shared__ __align__(16) unsigned short Bs[BN * BK];
  floatx4 acc[4][4];
  ACC_INIT(acc);
  const unsigned short* Qb = Q + (size_t)b * 2048 * 1024;
  const unsigned short* Kb = K + (size_t)b * 2048 * 1024;
  gemm_mainloop(Qb, 1024, Kb, 1024, m0, n0, 1024 / BK, As, Bs, acc);

  unsigned short* Sb = S + (size_t)b * 2048 * 2048;
  float* lb = lsum + b * 2048;
  const int tid = threadIdx.x, wave = tid >> 6, lane = tid & 63;
  const int wr = wave >> 1, wc = wave & 1;
  const int rb = m0 + wr * 64 + ((lane >> 4) << 2);
  const int cb = n0 + wc * 64 + (lane & 15);

  float rsum[4][4];
#pragma unroll
  for (int i = 0; i < 4; ++i)
#pragma unroll
    for (int r = 0; r < 4; ++r)
      rsum[i][r] = 0.f;

#pragma unroll
  for (int i = 0; i < 4; ++i)
#pragma unroll
    for (int j = 0; j < 4; ++j)
#pragma unroll
      for (int r = 0; r < 4; ++r) {
        const int tq = rb + i * 16 + r;
        const int tk = cb + j * 16;
        float e = 0.f;
        if (tk <= tq) e = __expf(acc[i][j][r] * 0.03125f);  // scale = 1/32
        const unsigned short h = f2bf(e);
        Sb[(size_t)tq * 2048 + tk] = h;
        rsum[i][r] += bf2f(h);   // l consistent with stored bf16 E
      }

  // reduce across the 16 lanes of each quad (same rows, different cols)
#pragma unroll
  for (int off = 1; off < 16; off <<= 1)
#pragma unroll
    for (int i = 0; i < 4; ++i)
#pragma unroll
      for (int r = 0; r < 4; ++r)
        rsum[i][r] += __shfl_xor(rsum[i][r], off, 64);

  if ((lane & 15) == 0) {
#pragma unroll
    for (int i = 0; i < 4; ++i)
#pragma unroll
      for (int r = 0; r < 4; ++r)
        atomicAdd(&lb[rb + i * 16 + r], rsum[i][r]);
  }
}

// out[b] = (E[b] @ V[b]) / l. b = blk & 7 (batch -> XCD), heavy mi first.
__global__ __launch_bounds__(256) void gemm_pv_kernel(
    const unsigned short* __restrict__ S,
    const unsigned short* __restrict__ Vt,
    const float* __restrict__ lsum,
    float* __restrict__ out)
{
  const int b = blockIdx.x & 7;
  const int r2 = blockIdx.x >> 3;              // 0..127
  const int mi = 15 - (r2 >> 3);               // heavy first (LPT)
  const int ni = r2 & 7;
  const int m0 = mi * BM;
  const int n0 = ni * BN;

  __shared__ __align__(16) unsigned short As[BM * BK];
  __shared__ __align__(16) unsigned short Bs[BN * BK];
  floatx4 acc[4][4];
  ACC_INIT(acc);
  const unsigned short* Pb = S  + (size_t)b * 2048 * 2048;   // lda 2048
  const unsigned short* Vb = Vt + (size_t)b * 1024 * 2048;   // ldb 2048
  const int kTiles = m0 / BK + BM / BK;                      // tk <= m0+127
  gemm_mainloop(Pb, 2048, Vb, 2048, m0, n0, kTiles, As, Bs, acc);

  float* Ob = out + (size_t)b * 2048 * 1024;
  const float* lb = lsum + b * 2048;
  const int tid = threadIdx.x, wave = tid >> 6, lane = tid & 63;
  const int wr = wave >> 1, wc = wave & 1;
  const int rb = m0 + wr * 64 + ((lane >> 4) << 2);
  const int cb = n0 + wc * 64 + (lane & 15);

  float inv[4][4];
#pragma unroll
  for (int i = 0; i < 4; ++i)
#pragma unroll
    for (int r = 0; r < 4; ++r)
      inv[i][r] = 1.0f / lb[rb + i * 16 + r];

#pragma unroll
  for (int i = 0; i < 4; ++i)
#pragma unroll
    for (int j = 0; j < 4; ++j)
#pragma unroll
      for (int r = 0; r < 4; ++r)
        Ob[(size_t)(rb + i * 16 + r) * 1024 + (cb + j * 16)] = acc[i][j][r] * inv[i][r];
}

// ---------------- launcher ----------------

extern "C" void kernel_launch(void* const* d_in, const int* in_sizes, int n_in,
                              void* d_out, int out_size, void* d_ws, size_t ws_size,
                              hipStream_t stream) {
  const float* x  = (const float*)d_in[0];
  const float* Wq = (const float*)d_in[1];
  const float* Wk = (const float*)d_in[2];
  const float* Wv = (const float*)d_in[3];
  float* out = (float*)d_out;

  char* ws = (char*)d_ws;
  unsigned short* xb  = (unsigned short*)(ws);                     //  33,554,432 B
  unsigned short* Wt  = (unsigned short*)(ws + 33554432ull);       //   6,291,456 B
  unsigned short* Q   = (unsigned short*)(ws + 39845888ull);       //  33,554,432 B
  unsigned short* K   = (unsigned short*)(ws + 73400320ull);       //  33,554,432 B
  unsigned short* V   = (unsigned short*)(ws + 106954752ull);      //  33,554,432 B
  unsigned short* Vt  = (unsigned short*)(ws + 140509184ull);      //  33,554,432 B
  unsigned short* S   = (unsigned short*)(ws + 174063616ull);      //  67,108,864 B
  float*          l   = (float*)ws;   // aliases xb: dead after QKV gemm
  // total ws use: 241,172,480 B

  cvt_x_kernel<<<16384, 256, 0, stream>>>(x, xb);
  dim3 gw(16, 16);
  cvt_w_kernel<<<gw, 256, 0, stream>>>(Wq, Wt);
  cvt_w_kernel<<<gw, 256, 0, stream>>>(Wk, Wt + 1024 * 1024);
  cvt_w_kernel<<<gw, 256, 0, stream>>>(Wv, Wt + 2 * 1024 * 1024);

  // 64 m-tiles x 12 n-tiles = 768 blocks (3 exact waves over 256 CUs)
  gemm_qkv_kernel<<<768, 512, 0, stream>>>(xb, Wt, Q, K, V);

  transpose_v_kernel<<<dim3(32, 16, 8), 256, 0, stream>>>(V, Vt);
  zero_l_kernel<<<64, 256, 0, stream>>>(l);   // after QKV: l aliases xb
  gemm_scores_kernel<<<8 * 136, 256, 0, stream>>>(Q, K, S, l);
  gemm_pv_kernel<<<1024, 256, 0, stream>>>(S, Vt, l, out);
}

// Round 4
// 350.683 us; speedup vs baseline: 1.1285x; 1.0432x over previous
//
#include <hip/hip_runtime.h>

// B=8, T=2048, C=1024, H=1024 single-head causal self-attention.
// R8: QKV = R6 kernel (best measured, 110.4 us). Scores/PV mainloop upgraded
// to BK=64 + verified 128B-row XOR swizzle (R7 formulas, 0 conflicts), single
// buffered 32 KB LDS -> keeps 2+ blocks/CU so co-resident blocks overlap
// read/MFMA phases (m114). cvt_x + 3x cvt_w + zero_l fused into one prep
// kernel (9 -> 5 launches); l gets its own ws slot (no xb aliasing).
//   1) prep: cvt x->bf16, cvt+transpose W*, zero l
//   2) QKV gemm -> Q,K,V    3) Vt[b][h][t] = V[b][t][h]
//   4) E = exp(scale*Q K^T) masked, l += rowsum
//   5) out = (E @ V) / l

typedef __attribute__((ext_vector_type(8))) __bf16 bf16x8;
typedef __attribute__((ext_vector_type(4))) float floatx4;

__device__ __forceinline__ unsigned short f2bf(float f) {
  unsigned int u = __float_as_uint(f);
  u += 0x7fffu + ((u >> 16) & 1u);   // round-to-nearest-even
  return (unsigned short)(u >> 16);
}
__device__ __forceinline__ float bf2f(unsigned short s) {
  return __uint_as_float(((unsigned int)s) << 16);
}

// global -> LDS direct DMA, 16B per lane. LDS dest is wave-uniform base + lane*16.
__device__ __forceinline__ void gload_lds16(const unsigned short* g, unsigned short* l) {
  __builtin_amdgcn_global_load_lds(
      (const __attribute__((address_space(1))) void*)g,
      (__attribute__((address_space(3))) void*)l,
      16, 0, 0);
}

// ---------------- 128x128 BK=64 swizzled mainloop (scores / PV) ----------------
// 4 waves (2x2 grid, 64x64 each), single-buffered As/Bs of 128x64 bf16 (16 KB
// each). Stage: 4 gload_lds/wave per operand-half... (4 instrs A + 4 instrs B
// per wave), pre-swizzled source chunk (l&7)^(l>>3); read chunk kq^(fr&7)
// (R7-verified conflict-free pair for 128B rows).
__device__ __forceinline__ void gemm_mainloop64(
    const unsigned short* __restrict__ A, int lda,
    const unsigned short* __restrict__ Bt, int ldb,
    int m0, int n0, int kSteps,
    unsigned short* As, unsigned short* Bs,
    floatx4 (&acc)[4][4])
{
  const int tid  = threadIdx.x;
  const int wave = tid >> 6;
  const int lane = tid & 63;
  const int wr = wave >> 1;
  const int wc = wave & 1;

  // staging: instr i of wave w covers rows w*32 + i*8 + (lane>>3), chunk lane&7
  // (LDS linear); global source chunk pre-swizzled by XOR row&7 (= lane>>3).
  const int rowIn = lane >> 3;                       // 0..7
  const int srcChunk = (((lane & 7) ^ rowIn) << 3);  // ushort offset 0..56

  const unsigned short* gA = A  + (size_t)(m0 + wave * 32 + rowIn) * lda + srcChunk;
  const unsigned short* gB = Bt + (size_t)(n0 + wave * 32 + rowIn) * ldb + srcChunk;
  const int lda8 = lda << 3;
  const int ldb8 = ldb << 3;

  // read-side swizzled addressing
  const int fr = lane & 15;
  const int kq = lane >> 4;                          // 0..3
  const int ac0 = ((kq ^ (fr & 7)) << 3);            // ksub 0
  const int ac1 = (((4 + kq) ^ (fr & 7)) << 3);      // ksub 1

  for (int kt = 0; kt < kSteps; ++kt) {
    __syncthreads();                 // prior iter's readers done before overwrite
#pragma unroll
    for (int i = 0; i < 4; ++i)
      gload_lds16(gA + i * lda8, As + (wave * 32 + i * 8) * 64);
#pragma unroll
    for (int i = 0; i < 4; ++i)
      gload_lds16(gB + i * ldb8, Bs + (wave * 32 + i * 8) * 64);
    gA += 64; gB += 64;
    __syncthreads();                 // vmcnt(0) drain: staging visible

    bf16x8 af[4], bg[4];
    // ksub 0
#pragma unroll
    for (int i = 0; i < 4; ++i)
      af[i] = *(const bf16x8*)(As + (wr * 64 + i * 16 + fr) * 64 + ac0);
#pragma unroll
    for (int j = 0; j < 4; ++j)
      bg[j] = *(const bf16x8*)(Bs + (wc * 64 + j * 16 + fr) * 64 + ac0);
#pragma unroll
    for (int i = 0; i < 4; ++i)
#pragma unroll
      for (int j = 0; j < 4; ++j)
        acc[i][j] = __builtin_amdgcn_mfma_f32_16x16x32_bf16(af[i], bg[j], acc[i][j], 0, 0, 0);
    // ksub 1
#pragma unroll
    for (int i = 0; i < 4; ++i)
      af[i] = *(const bf16x8*)(As + (wr * 64 + i * 16 + fr) * 64 + ac1);
#pragma unroll
    for (int j = 0; j < 4; ++j)
      bg[j] = *(const bf16x8*)(Bs + (wc * 64 + j * 16 + fr) * 64 + ac1);
#pragma unroll
    for (int i = 0; i < 4; ++i)
#pragma unroll
      for (int j = 0; j < 4; ++j)
        acc[i][j] = __builtin_amdgcn_mfma_f32_16x16x32_bf16(af[i], bg[j], acc[i][j], 0, 0, 0);
  }
}

#define ACC_INIT(acc)                         \
  do {                                        \
    floatx4 z_ = {0.f, 0.f, 0.f, 0.f};        \
    _Pragma("unroll")                         \
    for (int i_ = 0; i_ < 4; ++i_)            \
      _Pragma("unroll")                       \
      for (int j_ = 0; j_ < 4; ++j_)          \
        acc[i_][j_] = z_;                     \
  } while (0)

// ---------------- prep: cvt x, cvt+transpose W, zero l ----------------

__global__ __launch_bounds__(256) void prep_kernel(
    const float* __restrict__ x,
    const float* __restrict__ Wq,
    const float* __restrict__ Wk,
    const float* __restrict__ Wv,
    unsigned short* __restrict__ xb,
    unsigned short* __restrict__ Wt,
    float* __restrict__ l)
{
  const int bid = blockIdx.x;
  const int tid = threadIdx.x;
  if (bid < 16384) {
    // x [8,2048,1024] f32 -> xb bf16
    int idx = (bid * 256 + tid) * 4;
    float4 v = *(const float4*)(x + idx);
    ushort4 o;
    o.x = f2bf(v.x); o.y = f2bf(v.y); o.z = f2bf(v.z); o.w = f2bf(v.w);
    *(ushort4*)(xb + idx) = o;
  } else if (bid < 17152) {
    // W [1024 k,1024 n] f32 -> Wt [n,k] bf16  (3 weights x 256 tile-blocks)
    __shared__ unsigned short tile[64][65];
    const int wb = bid - 16384;
    const float* W = (wb < 256) ? Wq : (wb < 512) ? Wk : Wv;
    unsigned short* Wtp = Wt + (size_t)(wb >> 8) * 1048576;
    const int rem = wb & 255;
    const int k0 = (rem & 15) * 64, n0 = (rem >> 4) * 64;
    const int tx = tid & 63, ty = tid >> 6;
#pragma unroll
    for (int r = 0; r < 64; r += 4)
      tile[r + ty][tx] = f2bf(W[(size_t)(k0 + r + ty) * 1024 + (n0 + tx)]);
    __syncthreads();
#pragma unroll
    for (int r = 0; r < 64; r += 4)
      Wtp[(size_t)(n0 + r + ty) * 1024 + (k0 + tx)] = tile[tx][r + ty];
  } else {
    l[(bid - 17152) * 256 + tid] = 0.f;
  }
}

// ---------------- QKV: R6 256x256 4-phase counted pipeline (best measured) ----------------
__global__ __launch_bounds__(512, 2) void gemm_qkv_kernel(
    const unsigned short* __restrict__ xb,
    const unsigned short* __restrict__ Wt,
    unsigned short* __restrict__ Q,
    unsigned short* __restrict__ K,
    unsigned short* __restrict__ V)
{
  // 3 slots: A at slot*8192, B at 24576 + slot*8192 (ushorts). 96 KB total.
  __shared__ __align__(16) unsigned short lds[49152];

  // XCD map: bid&7 -> XCD; XCD x owns mi in [8x, 8x+8), ni-major walk.
  const int bid = blockIdx.x;
  const int xcd = bid & 7;
  const int local = bid >> 3;              // 0..95
  const int mi = xcd * 8 + (local & 7);    // 0..63
  const int ni = local >> 3;               // 0..11
  const int m0 = mi * 256;
  const int n0 = ni * 256;

  const int tid = threadIdx.x;
  const int w = tid >> 6;
  const int l = tid & 63;
  const int wr = w >> 2;              // 0..1 -> rows wr*128
  const int wc = w & 3;               // 0..3 -> cols wc*64

  // staging: dest row = w*16 + (l>>2), dest chunk = l&3; src chunk swizzled
  // by (row>>1)&3 = (l>>3)&3.
  const int sr0 = w * 16 + (l >> 2);
  const int scs = (((l & 3) ^ ((l >> 3) & 3)) << 3);   // ushort offset

  const unsigned short* pA0 = xb + (size_t)(m0 + sr0) * 1024 + scs;
  const unsigned short* pA1 = xb + (size_t)(m0 + 128 + sr0) * 1024 + scs;
  const unsigned short* pB0 = Wt + (size_t)(n0 + sr0) * 1024 + scs;
  const unsigned short* pB1 = Wt + (size_t)(n0 + 128 + sr0) * 1024 + scs;

  const int stgW = w * 512;           // wave's 16 rows x 32 ushorts

#define STAGE4(slot)                                             \
  do {                                                           \
    unsigned short* _sA = &lds[(slot) * 8192 + stgW];            \
    unsigned short* _sB = &lds[24576 + (slot) * 8192 + stgW];    \
    gload_lds16(pA0, _sA);                                       \
    gload_lds16(pA1, _sA + 4096);                                \
    gload_lds16(pB0, _sB);                                       \
    gload_lds16(pB1, _sB + 4096);                                \
    pA0 += 32; pA1 += 32; pB0 += 32; pB1 += 32;                  \
  } while (0)

  // read-side fragment addressing (same swizzle)
  const int fr = l & 15;              // fragment row
  const int q  = l >> 4;              // k quad (global chunk)
  const int cks = ((q ^ ((fr >> 1) & 3)) << 3);  // swizzled ushort offset
  const int aOff = (wr * 128 + fr) * 32 + cks;   // + i*512 per m-frag
  const int bOff = (wc * 64 + fr) * 32 + cks;    // + j*512 per n-frag

  floatx4 acc[8][4];
  {
    floatx4 z = {0.f, 0.f, 0.f, 0.f};
#pragma unroll
    for (int i = 0; i < 8; ++i)
#pragma unroll
      for (int j = 0; j < 4; ++j)
        acc[i][j] = z;
  }

  // prologue: stage tiles 0,1; gate on tile 0
  STAGE4(0);
  STAGE4(1);
  asm volatile("s_waitcnt vmcnt(4)" ::: "memory");   // tile 0 landed
  __builtin_amdgcn_s_barrier();

  bf16x8 a[8], b0[4], b1[4];
  {
    const unsigned short* sA = &lds[0];
    const unsigned short* sB = &lds[24576];
#pragma unroll
    for (int j = 0; j < 4; ++j) b0[j] = *(const bf16x8*)(sB + bOff + j * 512);
    a[0] = *(const bf16x8*)(sA + aOff);
    a[1] = *(const bf16x8*)(sA + aOff + 512);
  }

#define MFMA_PAIR(I0, BU)                                                           \
  do {                                                                              \
    __builtin_amdgcn_s_setprio(1);                                                  \
    _Pragma("unroll")                                                               \
    for (int j = 0; j < 4; ++j) {                                                   \
      acc[(I0)][j] =                                                                \
          __builtin_amdgcn_mfma_f32_16x16x32_bf16(a[(I0)], BU[j], acc[(I0)][j], 0, 0, 0); \
      acc[(I0) + 1][j] =                                                            \
          __builtin_amdgcn_mfma_f32_16x16x32_bf16(a[(I0) + 1], BU[j], acc[(I0) + 1][j], 0, 0, 0); \
    }                                                                               \
    __builtin_amdgcn_s_setprio(0);                                                  \
  } while (0)

#define ITER(KT, BU, BP)                                                  \
  do {                                                                    \
    const int nslot = (slot == 2) ? 0 : slot + 1;                         \
    const int sslot = (nslot == 2) ? 0 : nslot + 1;                       \
    const unsigned short* sA  = &lds[slot * 8192];                        \
    const unsigned short* sAn = &lds[nslot * 8192];                       \
    const unsigned short* sBn = &lds[24576 + nslot * 8192];               \
    unsigned short* dA = &lds[sslot * 8192 + stgW];                       \
    unsigned short* dB = &lds[24576 + sslot * 8192 + stgW];               \
    const bool doStage = ((KT) < 30);                                     \
    const bool doNext  = ((KT) < 31);                                     \
    a[2] = *(const bf16x8*)(sA + aOff + 2 * 512);                         \
    a[3] = *(const bf16x8*)(sA + aOff + 3 * 512);                         \
    if (doStage) gload_lds16(pA0, dA);                                    \
    __builtin_amdgcn_s_barrier();                                         \
    MFMA_PAIR(0, BU);                                                     \
    __builtin_amdgcn_s_barrier();                                         \
    a[4] = *(const bf16x8*)(sA + aOff + 4 * 512);                         \
    a[5] = *(const bf16x8*)(sA + aOff + 5 * 512);                         \
    if (doStage) gload_lds16(pA1, dA + 4096);                             \
    __builtin_amdgcn_s_barrier();                                         \
    MFMA_PAIR(2, BU);                                                     \
    __builtin_amdgcn_s_barrier();                                         \
    a[6] = *(const bf16x8*)(sA + aOff + 6 * 512);                         \
    a[7] = *(const bf16x8*)(sA + aOff + 7 * 512);                         \
    if (doStage) gload_lds16(pB0, dB);                                    \
    __builtin_amdgcn_s_barrier();                                         \
    MFMA_PAIR(4, BU);                                                     \
    __builtin_amdgcn_s_barrier();                                         \
    if (doStage) STAGE_LAST(dB);                                          \
    if (doNext) {                                                         \
      if (doStage) asm volatile("s_waitcnt vmcnt(3)" ::: "memory");       \
      else         asm volatile("s_waitcnt vmcnt(0)" ::: "memory");       \
      __builtin_amdgcn_s_barrier();                                       \
      _Pragma("unroll")                                                   \
      for (int j = 0; j < 4; ++j)                                         \
        BP[j] = *(const bf16x8*)(sBn + bOff + j * 512);                   \
      a[0] = *(const bf16x8*)(sAn + aOff);                                \
      a[1] = *(const bf16x8*)(sAn + aOff + 512);                          \
    }                                                                     \
    MFMA_PAIR(6, BU);                                                     \
    __builtin_amdgcn_s_barrier();                                         \
    slot = nslot;                                                         \
  } while (0)

#define STAGE_LAST(dB)                                                    \
  do {                                                                    \
    gload_lds16(pB1, (dB) + 4096);                                        \
    pA0 += 32; pA1 += 32; pB0 += 32; pB1 += 32;                           \
  } while (0)

  int slot = 0;
#pragma unroll 1
  for (int kt2 = 0; kt2 < 16; ++kt2) {
    const int kt = kt2 * 2;
    ITER(kt, b0, b1);        // even: consume b0, prefetch b1
    ITER(kt + 1, b1, b0);    // odd:  consume b1, prefetch b0
  }
#undef ITER
#undef STAGE_LAST
#undef MFMA_PAIR
#undef STAGE4

  // epilogue scatter: n0 block lies entirely in one of Q/K/V
  unsigned short* const dsts[3] = {Q, K, V};
  unsigned short* D = dsts[n0 >> 10];
  const int ncol0 = n0 & 1023;

  const int rb = m0 + wr * 128 + (q << 2);
  const int cb = ncol0 + wc * 64 + fr;
#pragma unroll
  for (int i = 0; i < 8; ++i)
#pragma unroll
    for (int j = 0; j < 4; ++j)
#pragma unroll
      for (int r = 0; r < 4; ++r)
        D[(size_t)(rb + i * 16 + r) * 1024 + (cb + j * 16)] = f2bf(acc[i][j][r]);
}

// Vt[b][h][t] = V[b*2048+t][h], ushort4 loads/stores
__global__ void transpose_v_kernel(const unsigned short* __restrict__ V,
                                   unsigned short* __restrict__ Vt) {
  __shared__ unsigned short tile[64][68];
  const int b = blockIdx.z;
  const int t0 = blockIdx.x * 64, h0 = blockIdx.y * 64;
  const int tid = threadIdx.x;
  const int cx = (tid & 15) * 4;
  const int ry = tid >> 4;               // 0..15
  const unsigned short* Vb = V + (size_t)b * 2048 * 1024;
#pragma unroll
  for (int r = 0; r < 64; r += 16) {
    ushort4 v = *(const ushort4*)(Vb + (size_t)(t0 + r + ry) * 1024 + (h0 + cx));
    *(ushort4*)&tile[r + ry][cx] = v;
  }
  __syncthreads();
  unsigned short* Vtb = Vt + (size_t)b * 1024 * 2048;
#pragma unroll
  for (int r = 0; r < 64; r += 16) {
    const int h = r + ry;
    ushort4 o;
    o.x = tile[cx][h]; o.y = tile[cx + 1][h]; o.z = tile[cx + 2][h]; o.w = tile[cx + 3][h];
    *(ushort4*)(Vtb + (size_t)(h0 + h) * 2048 + (t0 + cx)) = o;
  }
}

// E[b] = exp(scale * Q[b] K[b]^T), causal; l[b,i] += row sums.
// grid 8*136; b = blk & 7 (batch -> XCD), t = blk >> 3 (tri-tile, mi-grouped).
__global__ __launch_bounds__(256) void gemm_scores_kernel(
    const unsigned short* __restrict__ Q,
    const unsigned short* __restrict__ K,
    unsigned short* __restrict__ S,
    float* __restrict__ lsum)
{
  const int b = blockIdx.x & 7;
  const int t = blockIdx.x >> 3;
  int mi = (int)((sqrtf(8.f * (float)t + 1.f) - 1.f) * 0.5f);
  while ((mi + 1) * (mi + 2) / 2 <= t) ++mi;   // fp guard
  while (mi * (mi + 1) / 2 > t) --mi;
  const int ni = t - mi * (mi + 1) / 2;
  const int m0 = mi * 128;
  const int n0 = ni * 128;

  __shared__ __align__(16) unsigned short As[128 * 64];
  __shared__ __align__(16) unsigned short Bs[128 * 64];
  floatx4 acc[4][4];
  ACC_INIT(acc);
  const unsigned short* Qb = Q + (size_t)b * 2048 * 1024;
  const unsigned short* Kb = K + (size_t)b * 2048 * 1024;
  gemm_mainloop64(Qb, 1024, Kb, 1024, m0, n0, 16, As, Bs, acc);

  unsigned short* Sb = S + (size_t)b * 2048 * 2048;
  float* lb = lsum + b * 2048;
  const int tid = threadIdx.x, wave = tid >> 6, lane = tid & 63;
  const int wr = wave >> 1, wc = wave & 1;
  const int rb = m0 + wr * 64 + ((lane >> 4) << 2);
  const int cb = n0 + wc * 64 + (lane & 15);

  float rsum[4][4];
#pragma unroll
  for (int i = 0; i < 4; ++i)
#pragma unroll
    for (int r = 0; r < 4; ++r)
      rsum[i][r] = 0.f;

#pragma unroll
  for (int i = 0; i < 4; ++i)
#pragma unroll
    for (int j = 0; j < 4; ++j)
#pragma unroll
      for (int r = 0; r < 4; ++r) {
        const int tq = rb + i * 16 + r;
        const int tk = cb + j * 16;
        float e = 0.f;
        if (tk <= tq) e = __expf(acc[i][j][r] * 0.03125f);  // scale = 1/32
        const unsigned short h = f2bf(e);
        Sb[(size_t)tq * 2048 + tk] = h;
        rsum[i][r] += bf2f(h);   // l consistent with stored bf16 E
      }

  // reduce across the 16 lanes of each quad (same rows, different cols)
#pragma unroll
  for (int off = 1; off < 16; off <<= 1)
#pragma unroll
    for (int i = 0; i < 4; ++i)
#pragma unroll
      for (int r = 0; r < 4; ++r)
        rsum[i][r] += __shfl_xor(rsum[i][r], off, 64);

  if ((lane & 15) == 0) {
#pragma unroll
    for (int i = 0; i < 4; ++i)
#pragma unroll
      for (int r = 0; r < 4; ++r)
        atomicAdd(&lb[rb + i * 16 + r], rsum[i][r]);
  }
}

// out[b] = (E[b] @ V[b]) / l. b = blk & 7 (batch -> XCD), heavy mi first.
__global__ __launch_bounds__(256) void gemm_pv_kernel(
    const unsigned short* __restrict__ S,
    const unsigned short* __restrict__ Vt,
    const float* __restrict__ lsum,
    float* __restrict__ out)
{
  const int b = blockIdx.x & 7;
  const int r2 = blockIdx.x >> 3;              // 0..127
  const int mi = 15 - (r2 >> 3);               // heavy first (LPT)
  const int ni = r2 & 7;
  const int m0 = mi * 128;
  const int n0 = ni * 128;

  __shared__ __align__(16) unsigned short As[128 * 64];
  __shared__ __align__(16) unsigned short Bs[128 * 64];
  floatx4 acc[4][4];
  ACC_INIT(acc);
  const unsigned short* Pb = S  + (size_t)b * 2048 * 2048;   // lda 2048
  const unsigned short* Vb = Vt + (size_t)b * 1024 * 2048;   // ldb 2048
  const int kSteps = m0 / 64 + 2;                            // tk <= m0+127
  gemm_mainloop64(Pb, 2048, Vb, 2048, m0, n0, kSteps, As, Bs, acc);

  float* Ob = out + (size_t)b * 2048 * 1024;
  const float* lb = lsum + b * 2048;
  const int tid = threadIdx.x, wave = tid >> 6, lane = tid & 63;
  const int wr = wave >> 1, wc = wave & 1;
  const int rb = m0 + wr * 64 + ((lane >> 4) << 2);
  const int cb = n0 + wc * 64 + (lane & 15);

  float inv[4][4];
#pragma unroll
  for (int i = 0; i < 4; ++i)
#pragma unroll
    for (int r = 0; r < 4; ++r)
      inv[i][r] = 1.0f / lb[rb + i * 16 + r];

#pragma unroll
  for (int i = 0; i < 4; ++i)
#pragma unroll
    for (int j = 0; j < 4; ++j)
#pragma unroll
      for (int r = 0; r < 4; ++r)
        Ob[(size_t)(rb + i * 16 + r) * 1024 + (cb + j * 16)] = acc[i][j][r] * inv[i][r];
}

// ---------------- launcher ----------------

extern "C" void kernel_launch(void* const* d_in, const int* in_sizes, int n_in,
                              void* d_out, int out_size, void* d_ws, size_t ws_size,
                              hipStream_t stream) {
  const float* x  = (const float*)d_in[0];
  const float* Wq = (const float*)d_in[1];
  const float* Wk = (const float*)d_in[2];
  const float* Wv = (const float*)d_in[3];
  float* out = (float*)d_out;

  char* ws = (char*)d_ws;
  unsigned short* xb  = (unsigned short*)(ws);                     //  33,554,432 B
  unsigned short* Wt  = (unsigned short*)(ws + 33554432ull);       //   6,291,456 B
  unsigned short* Q   = (unsigned short*)(ws + 39845888ull);       //  33,554,432 B
  unsigned short* K   = (unsigned short*)(ws + 73400320ull);       //  33,554,432 B
  unsigned short* V   = (unsigned short*)(ws + 106954752ull);      //  33,554,432 B
  unsigned short* Vt  = (unsigned short*)(ws + 140509184ull);      //  33,554,432 B
  unsigned short* S   = (unsigned short*)(ws + 174063616ull);      //  67,108,864 B
  float*          l   = (float*)(ws + 241172480ull);               //      65,536 B
  // total ws use: 241,238,016 B

  prep_kernel<<<17216, 256, 0, stream>>>(x, Wq, Wk, Wv, xb, Wt, l);

  // 64 m-tiles x 12 n-tiles = 768 blocks
  gemm_qkv_kernel<<<768, 512, 0, stream>>>(xb, Wt, Q, K, V);

  transpose_v_kernel<<<dim3(32, 16, 8), 256, 0, stream>>>(V, Vt);
  gemm_scores_kernel<<<8 * 136, 256, 0, stream>>>(Q, K, S, l);
  gemm_pv_kernel<<<1024, 256, 0, stream>>>(S, Vt, l, out);
}